// Round 1
// baseline (67.758 us; speedup 1.0000x reference)
//
#include <hip/hip_runtime.h>

// Cox PH loss, N=8192 fp32.
// R3: LDS-staged scan table. Each block stages all 8192 (survtime_j, exp(theta_j))
// pairs into LDS once (coalesced float2/float loads, exp computed during staging),
// then the j-scan runs entirely from LDS (ds_read_b64, 2-way aliasing = free).
// IPB 8->16 halves block count (512 blocks = 2/CU, LDS-limited) and halves the
// redundant global scan traffic. Inner loop: 16 independent cmp/sel/add chains
// per loaded j -> VALU-bound (~2.6 us floor), no L2 latency on the critical path.

#define COX_N 8192
#define TPB   256
#define IPB   16                // i's owned per block (register-blocked per thread)
#define NBLK  (COX_N / IPB)     // 512 blocks
#define JPT   (COX_N / TPB)     // 32 j-iterations per thread
#define NWAVE (TPB / 64)        // 4 waves per block

__global__ __launch_bounds__(TPB, 2) void cox_main(const float* __restrict__ y,
                                                   const float* __restrict__ theta,
                                                   float* __restrict__ partial) {
    const int t  = threadIdx.x;
    const int b  = blockIdx.x;
    const int i0 = b * IPB;

    __shared__ float2 s[COX_N];            // 64 KB: (survtime_j, exp(theta_j))
    __shared__ float  s_red[IPB][NWAVE];   // cross-wave reduction scratch

    const float2* __restrict__ y2 = (const float2*)y;  // y is (N,2) row-major

    // Stage: thread t covers j = t + m*256. Coalesced 8B y-pair + 4B theta loads,
    // exp computed once per block (vs once per j-visit before).
#pragma unroll 8
    for (int m = 0; m < JPT; ++m) {
        const int    j  = t + m * TPB;
        const float2 yv = y2[j];                 // {survtime_j, censor_j}
        const float  e  = __expf(theta[j]);
        s[j] = make_float2(yv.x, e);
    }
    __syncthreads();

    float st[IPB], acc[IPB];
#pragma unroll
    for (int r = 0; r < IPB; ++r) { st[r] = s[i0 + r].x; acc[r] = 0.f; }  // broadcast reads

    // Scan all j from LDS; each loaded (stj, ej) feeds 16 independent chains.
#pragma unroll 4
    for (int k = 0; k < JPT; ++k) {
        const float2 p = s[t + k * TPB];         // ds_read_b64, stride-1, conflict-free
#pragma unroll
        for (int r = 0; r < IPB; ++r)
            acc[r] += (p.x >= st[r]) ? p.y : 0.f;
    }

    // Wave-level reduce each accumulator, then cross-wave via LDS.
    const int lane = t & 63, wave = t >> 6;
#pragma unroll
    for (int r = 0; r < IPB; ++r) {
        float v = acc[r];
        for (int off = 32; off > 0; off >>= 1)
            v += __shfl_down(v, off, 64);
        if (lane == 0) s_red[r][wave] = v;
    }
    __syncthreads();

    // Wave 0: lanes 0..15 finish their i; reduce 16 terms; one store per block.
    if (wave == 0) {
        float term = 0.f;
        if (t < IPB) {
            float risk = 0.f;
#pragma unroll
            for (int w = 0; w < NWAVE; ++w) risk += s_red[t][w];
            const int   i      = i0 + t;
            const float censor = (y[2 * i + 1] != 0.f) ? 1.f : 0.f;
            term = (theta[i] - __logf(risk)) * censor;
        }
        term += __shfl_down(term, 8, 64);
        term += __shfl_down(term, 4, 64);
        term += __shfl_down(term, 2, 64);
        term += __shfl_down(term, 1, 64);
        if (t == 0) partial[b] = term;
    }
}

__global__ __launch_bounds__(TPB) void cox_fin(const float* __restrict__ partial,
                                               float* __restrict__ out) {
    const int t = threadIdx.x;
    float v = partial[t] + partial[t + 256];     // NBLK = 512
    for (int off = 32; off > 0; off >>= 1)
        v += __shfl_down(v, off, 64);
    __shared__ float red[NWAVE];
    if ((t & 63) == 0) red[t >> 6] = v;
    __syncthreads();
    if (t == 0) out[0] = -(red[0] + red[1] + red[2] + red[3]) / (float)COX_N;
}

extern "C" void kernel_launch(void* const* d_in, const int* in_sizes, int n_in,
                              void* d_out, int out_size, void* d_ws, size_t ws_size,
                              hipStream_t stream) {
    const float* y     = (const float*)d_in[0];  // (N,2): [survtime, censor]
    const float* theta = (const float*)d_in[1];  // (N,1)
    float* part = (float*)d_ws;                  // NBLK floats = 2 KB scratch
    float* out  = (float*)d_out;

    cox_main<<<dim3(NBLK), dim3(TPB), 0, stream>>>(y, theta, part);
    cox_fin<<<dim3(1), dim3(TPB), 0, stream>>>(part, out);
}